// Round 10
// baseline (8024.181 us; speedup 1.0000x reference)
//
#include <hip/hip_runtime.h>
#include <hip/hip_fp16.h>
#include <math.h>

#define NN 50000
#define NE 600000
#define H 128
#define TWO_H 256
#define THREE_H 384
#define NLAYER 10

typedef __attribute__((ext_vector_type(4))) float f32x4;
typedef __attribute__((ext_vector_type(8))) short s16x8;
typedef _Float16 f16x8 __attribute__((ext_vector_type(8)));

__device__ __forceinline__ float gelu_f(float x) {
    return 0.5f * x * (1.0f + erff(x * 0.70710678118654752f));
}

// tanh-form GELU: max |err vs exact| ~3e-4, ~9 VALU ops (HW v_exp/v_rcp)
__device__ __forceinline__ float gelu_fast(float x) {
    float u = x * fmaf(0.044715f, x * x, 1.0f);
    float e = __expf(1.5957691216057308f * u);
    return x * (1.0f - __builtin_amdgcn_rcpf(e + 1.0f));
}

__device__ __forceinline__ float wave_reduce_add64(float v) {
#pragma unroll
    for (int m = 32; m >= 1; m >>= 1) v += __shfl_xor(v, m);
    return v;
}

__global__ void signal_kernel(float* __restrict__ out, int n, float val) {
    int i = blockIdx.x * blockDim.x + threadIdx.x;
    if (i < n) out[i] = val;
}

// ---------------- weight prep: fp32 [L][K][N] -> fp16 [L][N][K] ----------------
__global__ void transpose_cvt_kernel(const float* __restrict__ src,
                                     __half* __restrict__ dst,
                                     int K, int N, int total) {
    int i = blockIdx.x * 256 + threadIdx.x;
    if (i >= total) return;
    int n = i % N;
    int lk = i / N;
    int k = lk % K;
    int l = lk / K;
    dst[((size_t)l * N + n) * K + k] = __float2half_rn(src[i]);
}

// ---------------- encoder: h = GELU(LN(x @ enc_w + enc_b)) -> fp16 ----------------
__global__ __launch_bounds__(128) void encoder_kernel(
    const float* __restrict__ x, const float* __restrict__ w,
    const float* __restrict__ b, const float* __restrict__ g,
    const float* __restrict__ bb, __half* __restrict__ hh) {
    int n = blockIdx.x;
    int j = threadIdx.x;
    __shared__ float xs[3];
    __shared__ float2 red[2];
    if (j < 3) xs[j] = x[n * 3 + j];
    __syncthreads();
    float v = b[j] + xs[0] * w[j] + xs[1] * w[H + j] + xs[2] * w[2 * H + j];
    float s = v, sq = v * v;
    s = wave_reduce_add64(s);
    sq = wave_reduce_add64(sq);
    if ((j & 63) == 0) red[j >> 6] = make_float2(s, sq);
    __syncthreads();
    float ts = red[0].x + red[1].x;
    float tq = red[0].y + red[1].y;
    float m = ts * (1.0f / 128.0f);
    float var = tq * (1.0f / 128.0f) - m * m;
    float rs = rsqrtf(var + 1e-5f);
    hh[(size_t)n * H + j] = __float2half_rn(gelu_f((v - m) * rs * g[j] + bb[j]));
}

// ---------------- edge encoder ----------------
__global__ __launch_bounds__(128) void eenc_kernel(
    const float* __restrict__ attr, const float* __restrict__ w,
    const float* __restrict__ b, __half* __restrict__ ea) {
    int e = blockIdx.x;
    int j = threadIdx.x;
    __shared__ float as_[8];
    if (j < 8) as_[j] = attr[(size_t)e * 8 + j];
    __syncthreads();
    float v = b[j];
#pragma unroll
    for (int k = 0; k < 8; k++) v += as_[k] * w[k * H + j];
    ea[(size_t)e * H + j] = __float2half_rn(v);
}

__global__ void count_kernel(const int* __restrict__ col, int* __restrict__ cnt) {
    int i = blockIdx.x * blockDim.x + threadIdx.x;
    if (i < NE) atomicAdd(&cnt[col[i]], 1);
}

__global__ __launch_bounds__(1024) void scan_kernel(
    const int* __restrict__ cnt, int* __restrict__ rstart, float* __restrict__ cntf) {
    __shared__ int buf[1024];
    __shared__ int s_carry;
    int tid = threadIdx.x;
    if (tid == 0) s_carry = 0;
    __syncthreads();
    for (int base = 0; base < NN; base += 1024) {
        int i = base + tid;
        int v = (i < NN) ? cnt[i] : 0;
        buf[tid] = v;
        __syncthreads();
        for (int off = 1; off < 1024; off <<= 1) {
            int add = (tid >= off) ? buf[tid - off] : 0;
            __syncthreads();
            buf[tid] += add;
            __syncthreads();
        }
        int incl = buf[tid];
        int cv = s_carry;
        if (i < NN) {
            rstart[i] = cv + incl - v;
            cntf[i] = (float)(v > 1 ? v : 1);
        }
        __syncthreads();
        if (tid == 0) s_carry = cv + buf[1023];
        __syncthreads();
    }
    if (threadIdx.x == 0) rstart[NN] = s_carry;
}

__global__ void init_fill_kernel(const int* __restrict__ rstart, int* __restrict__ fptr) {
    int i = blockIdx.x * blockDim.x + threadIdx.x;
    if (i < NN) fptr[i] = rstart[i];
}

__global__ void fill_kernel(const int* __restrict__ col, int* __restrict__ fptr,
                            int* __restrict__ elist) {
    int i = blockIdx.x * blockDim.x + threadIdx.x;
    if (i < NE) {
        int c = col[i];
        int p = atomicAdd(&fptr[c], 1);
        elist[p] = i;
    }
}

// ---------------- CSR mean aggregation ----------------
__global__ __launch_bounds__(128) void aggregate_kernel(
    const __half* __restrict__ ea, const int* __restrict__ elist,
    const int* __restrict__ rstart, const float* __restrict__ cntf,
    __half* __restrict__ agg) {
    int n = blockIdx.x;
    int t = threadIdx.x;
    int s = rstart[n], e_end = rstart[n + 1];
    float sum = 0.0f;
    for (int p = s; p < e_end; ++p) {
        int e = elist[p];
        sum += __half2float(ea[(size_t)e * H + t]);
    }
    agg[(size_t)n * H + t] = __float2half_rn(sum / cntf[n]);
}

// ---------------- fused f16-MFMA MLP, 512 threads / 8 waves ----------------
// 64 rows/block. Wave w: GEMM1 cols [w*32,+32) (2 ct), GEMM2 cols [w*16,+16) (1 ct).
// 3 blocks/CU (LDS ~54KB) -> 24 waves/CU target occupancy.
// EDGE: in=[hh[row]|hh[col]|ea] K=384, resid=ea. NODE: in=[hh|agg] K=256, resid=hh.
template <bool EDGE>
__global__ __launch_bounds__(512, 6) void mlp_mfma(
    __half* hh, __half* ea, const __half* __restrict__ agg,
    const int* __restrict__ eidx,
    const __half* __restrict__ w1T, const float* __restrict__ b1,
    const float* __restrict__ g1, const float* __restrict__ bb1,
    const __half* __restrict__ w2T, const float* __restrict__ b2,
    const float* __restrict__ g2, const float* __restrict__ bb2,
    int nrows) {
    constexpr int KIN = EDGE ? THREE_H : TWO_H;
    constexpr int ALD = KIN + 8;   // halves; odd word-stride rows
    constexpr int ZLD = TWO_H + 8; // 264

    __shared__ __align__(16) short A_s[64 * ALD];
    __shared__ float2 red[64][8];
    short* z_s = A_s;  // z tile [64][264] aliases A_s

    const int t = threadIdx.x;
    const int wave = t >> 6;      // 0..7
    const int lane = t & 63;
    const int lanelo = lane & 15;
    const int grp = lane >> 4;
    const size_t r0 = (size_t)blockIdx.x * 64;

    // ---- stage A: fp16 bit-copies, 8 threads per row ----
    {
        int r = t >> 3;      // 0..63
        int ph = t & 7;
        size_t row_g = r0 + r;
        const short* s0;
        const short* s1 = nullptr;
        const short* s2;
        if constexpr (EDGE) {
            int ri = eidx[row_g];
            int ci = eidx[NE + row_g];
            s0 = (const short*)hh + (size_t)ri * H;
            s1 = (const short*)hh + (size_t)ci * H;
            s2 = (const short*)ea + row_g * H;
        } else {
            size_t n = row_g < (size_t)nrows ? row_g : (size_t)(nrows - 1);
            s0 = (const short*)hh + n * H;
            s2 = (const short*)agg + n * H;
        }
        short* arow = A_s + r * ALD;
#pragma unroll
        for (int k = ph * 8; k < KIN; k += 64) {
            s16x8 sv;
            if constexpr (EDGE) {
                if (k < H) sv = *(const s16x8*)(s0 + k);
                else if (k < 2 * H) sv = *(const s16x8*)(s1 + (k - H));
                else sv = *(const s16x8*)(s2 + (k - 2 * H));
            } else {
                sv = (k < H) ? *(const s16x8*)(s0 + k) : *(const s16x8*)(s2 + (k - H));
            }
            *(s16x8*)(arow + k) = sv;
        }
    }
    __syncthreads();

    // ---- GEMM1: z[64][256] = A @ w1 (2 col-tiles per wave) ----
    f32x4 acc[4][2];
#pragma unroll
    for (int rt = 0; rt < 4; rt++)
#pragma unroll
        for (int ct = 0; ct < 2; ct++) acc[rt][ct] = (f32x4){0.f, 0.f, 0.f, 0.f};

    const int c1 = wave * 32 + lanelo;  // +ct*16
    for (int ks = 0; ks < KIN / 32; ++ks) {
        const int k0 = ks * 32 + grp * 8;
        f16x8 a[4], b[2];
#pragma unroll
        for (int rt = 0; rt < 4; rt++)
            a[rt] = *(const f16x8*)(const void*)(A_s + (rt * 16 + lanelo) * ALD + k0);
#pragma unroll
        for (int ct = 0; ct < 2; ct++)
            b[ct] = *(const f16x8*)(const void*)(w1T + (size_t)(c1 + ct * 16) * KIN + k0);
#pragma unroll
        for (int rt = 0; rt < 4; rt++)
#pragma unroll
            for (int ct = 0; ct < 2; ct++)
                acc[rt][ct] = __builtin_amdgcn_mfma_f32_16x16x32_f16(
                    a[rt], b[ct], acc[rt][ct], 0, 0, 0);
    }

    // ---- fold bias, LN1 partials ----
#pragma unroll
    for (int ct = 0; ct < 2; ct++) {
        float bc = b1[c1 + ct * 16];
#pragma unroll
        for (int rt = 0; rt < 4; rt++)
#pragma unroll
            for (int i = 0; i < 4; i++) acc[rt][ct][i] += bc;
    }
#pragma unroll
    for (int rt = 0; rt < 4; rt++)
#pragma unroll
        for (int i = 0; i < 4; i++) {
            float z0 = acc[rt][0][i], z1 = acc[rt][1][i];
            float s = z0 + z1;
            float q = z0 * z0 + z1 * z1;
            s += __shfl_xor(s, 1); s += __shfl_xor(s, 2);
            s += __shfl_xor(s, 4); s += __shfl_xor(s, 8);
            q += __shfl_xor(q, 1); q += __shfl_xor(q, 2);
            q += __shfl_xor(q, 4); q += __shfl_xor(q, 8);
            if (lanelo == 0) red[rt * 16 + grp * 4 + i][wave] = make_float2(s, q);
        }
    __syncthreads();  // fences A_s reads -> z_s writes safe

    // ---- LN1 apply + fast GELU + write z fp16 ----
    {
        float g1c[2], bb1c[2];
#pragma unroll
        for (int ct = 0; ct < 2; ct++) { g1c[ct] = g1[c1 + ct * 16]; bb1c[ct] = bb1[c1 + ct * 16]; }
#pragma unroll
        for (int rt = 0; rt < 4; rt++)
#pragma unroll
            for (int i = 0; i < 4; i++) {
                int r = rt * 16 + grp * 4 + i;
                float sum = 0.f, sq = 0.f;
#pragma unroll
                for (int w = 0; w < 8; w++) { float2 pw = red[r][w]; sum += pw.x; sq += pw.y; }
                float m = sum * (1.f / 256.f);
                float var = sq * (1.f / 256.f) - m * m;
                float rs = rsqrtf(var + 1e-5f);
#pragma unroll
                for (int ct = 0; ct < 2; ct++) {
                    float v = (acc[rt][ct][i] - m) * rs * g1c[ct] + bb1c[ct];
                    __half hv = __float2half_rn(gelu_fast(v));
                    z_s[r * ZLD + c1 + ct * 16] = __half_as_short(hv);
                }
            }
    }
    __syncthreads();

    // ---- GEMM2: d[64][128] = z @ w2 (1 col-tile per wave) ----
    f32x4 acc2[4];
#pragma unroll
    for (int rt = 0; rt < 4; rt++) acc2[rt] = (f32x4){0.f, 0.f, 0.f, 0.f};

    const int c2 = wave * 16 + lanelo;
    for (int ks = 0; ks < TWO_H / 32; ++ks) {
        const int k0 = ks * 32 + grp * 8;
        f16x8 a2[4], b2v;
#pragma unroll
        for (int rt = 0; rt < 4; rt++)
            a2[rt] = *(const f16x8*)(const void*)(z_s + (rt * 16 + lanelo) * ZLD + k0);
        b2v = *(const f16x8*)(const void*)(w2T + (size_t)c2 * TWO_H + k0);
#pragma unroll
        for (int rt = 0; rt < 4; rt++)
            acc2[rt] = __builtin_amdgcn_mfma_f32_16x16x32_f16(a2[rt], b2v, acc2[rt], 0, 0, 0);
    }

    // ---- fold bias, LN2 partials ----
    {
        float bc = b2[c2];
#pragma unroll
        for (int rt = 0; rt < 4; rt++)
#pragma unroll
            for (int i = 0; i < 4; i++) acc2[rt][i] += bc;
    }
#pragma unroll
    for (int rt = 0; rt < 4; rt++)
#pragma unroll
        for (int i = 0; i < 4; i++) {
            float z = acc2[rt][i];
            float s = z, q = z * z;
            s += __shfl_xor(s, 1); s += __shfl_xor(s, 2);
            s += __shfl_xor(s, 4); s += __shfl_xor(s, 8);
            q += __shfl_xor(q, 1); q += __shfl_xor(q, 2);
            q += __shfl_xor(q, 4); q += __shfl_xor(q, 8);
            if (lanelo == 0) red[rt * 16 + grp * 4 + i][wave] = make_float2(s, q);
        }
    __syncthreads();

    // ---- LN2 apply + residual RMW (fp16 state) ----
    {
        float g2c = g2[c2], bb2c = bb2[c2];
#pragma unroll
        for (int rt = 0; rt < 4; rt++)
#pragma unroll
            for (int i = 0; i < 4; i++) {
                int r = rt * 16 + grp * 4 + i;
                float sum = 0.f, sq = 0.f;
#pragma unroll
                for (int w = 0; w < 8; w++) { float2 pw = red[r][w]; sum += pw.x; sq += pw.y; }
                float m = sum * (1.f / 128.f);
                float var = sq * (1.f / 128.f) - m * m;
                float rs = rsqrtf(var + 1e-5f);
                size_t rowg = r0 + r;
                float d = (acc2[rt][i] - m) * rs * g2c + bb2c;
                size_t idx = rowg * H + c2;
                if constexpr (EDGE) {
                    ea[idx] = __float2half_rn(__half2float(ea[idx]) + d);
                } else {
                    if (rowg < (size_t)nrows)
                        hh[idx] = __float2half_rn(__half2float(hh[idx]) + d);
                }
            }
    }
}

// ---------------- decoder ----------------
__global__ __launch_bounds__(128) void decoder_kernel(
    const __half* __restrict__ hh, const float* __restrict__ w1,
    const float* __restrict__ b1, const float* __restrict__ w2,
    const float* __restrict__ b2, float* __restrict__ out) {
    int n = blockIdx.x;
    int j = threadIdx.x;
    __shared__ float hs[128];
    __shared__ float4 red[2];
    hs[j] = __half2float(hh[(size_t)n * H + j]);
    __syncthreads();
    float t1 = b1[j];
#pragma unroll 8
    for (int k = 0; k < 128; k++) t1 += hs[k] * w1[k * H + j];
    t1 = gelu_f(t1);
    float4 w = *(const float4*)(w2 + j * 4);
    float4 p = make_float4(t1 * w.x, t1 * w.y, t1 * w.z, t1 * w.w);
#pragma unroll
    for (int m = 32; m >= 1; m >>= 1) {
        p.x += __shfl_xor(p.x, m);
        p.y += __shfl_xor(p.y, m);
        p.z += __shfl_xor(p.z, m);
        p.w += __shfl_xor(p.w, m);
    }
    if ((j & 63) == 0) red[j >> 6] = p;
    __syncthreads();
    if (j == 0) {
        out[(size_t)n * 4 + 0] = red[0].x + red[1].x + b2[0];
        out[(size_t)n * 4 + 1] = red[0].y + red[1].y + b2[1];
        out[(size_t)n * 4 + 2] = red[0].z + red[1].z + b2[2];
        out[(size_t)n * 4 + 3] = red[0].w + red[1].w + b2[3];
    }
}

extern "C" void kernel_launch(void* const* d_in, const int* in_sizes, int n_in,
                              void* d_out, int out_size, void* d_ws, size_t ws_size,
                              hipStream_t stream) {
    const float* x = (const float*)d_in[0];
    const int* eidx = (const int*)d_in[1];
    const float* eattr = (const float*)d_in[2];
    const float* enc_w = (const float*)d_in[3];
    const float* enc_b = (const float*)d_in[4];
    const float* enc_g = (const float*)d_in[5];
    const float* enc_bb = (const float*)d_in[6];
    const float* eenc_w = (const float*)d_in[7];
    const float* eenc_b = (const float*)d_in[8];
    const float* e_w1 = (const float*)d_in[9];
    const float* e_b1 = (const float*)d_in[10];
    const float* e_g1 = (const float*)d_in[11];
    const float* e_bb1 = (const float*)d_in[12];
    const float* e_w2 = (const float*)d_in[13];
    const float* e_b2 = (const float*)d_in[14];
    const float* e_g2 = (const float*)d_in[15];
    const float* e_bb2 = (const float*)d_in[16];
    const float* n_w1 = (const float*)d_in[17];
    const float* n_b1 = (const float*)d_in[18];
    const float* n_g1 = (const float*)d_in[19];
    const float* n_bb1 = (const float*)d_in[20];
    const float* n_w2 = (const float*)d_in[21];
    const float* n_b2 = (const float*)d_in[22];
    const float* n_g2 = (const float*)d_in[23];
    const float* n_bb2 = (const float*)d_in[24];
    const float* dec_w1 = (const float*)d_in[25];
    const float* dec_b1 = (const float*)d_in[26];
    const float* dec_w2 = (const float*)d_in[27];
    const float* dec_b2 = (const float*)d_in[28];
    float* out = (float*)d_out;
    (void)in_sizes; (void)n_in;

    auto AL = [](size_t b) { return (b + 255) & ~(size_t)255; };
    const size_t sz_hh = AL((size_t)NN * H * 2);
    const size_t sz_ea = AL((size_t)NE * H * 2);
    const size_t sz_agg = AL((size_t)NN * H * 2);
    const size_t sz_cntf = AL((size_t)NN * 4);
    const size_t sz_cnt = AL((size_t)NN * 4);
    const size_t sz_rst = AL((size_t)(NN + 1) * 4);
    const size_t sz_fptr = AL((size_t)NN * 4);
    const size_t sz_elist = AL((size_t)NE * 4);
    const size_t sz_ew1 = AL((size_t)NLAYER * TWO_H * THREE_H * 2);
    const size_t sz_ew2 = AL((size_t)NLAYER * H * TWO_H * 2);
    const size_t sz_nw1 = AL((size_t)NLAYER * TWO_H * TWO_H * 2);
    const size_t sz_nw2 = AL((size_t)NLAYER * H * TWO_H * 2);
    const size_t need = sz_hh + sz_ea + sz_agg + sz_cntf + sz_cnt + sz_rst +
                        sz_fptr + sz_elist + sz_ew1 + sz_ew2 + sz_nw1 + sz_nw2;

    if (ws_size < need) {
        float sig = 1000.0f + (float)(ws_size >> 20);
        signal_kernel<<<(out_size + 255) / 256, 256, 0, stream>>>(out, out_size, sig);
        return;
    }

    char* p = (char*)d_ws;
    auto alloc = [&](size_t bytes) { void* r = (void*)p; p += bytes; return r; };
    __half* hh = (__half*)alloc(sz_hh);
    __half* ea = (__half*)alloc(sz_ea);
    __half* agg = (__half*)alloc(sz_agg);
    float* cntf = (float*)alloc(sz_cntf);
    int* cnt = (int*)alloc(sz_cnt);
    int* rstart = (int*)alloc(sz_rst);
    int* fptr = (int*)alloc(sz_fptr);
    int* elist = (int*)alloc(sz_elist);
    __half* ew1T = (__half*)alloc(sz_ew1);
    __half* ew2T = (__half*)alloc(sz_ew2);
    __half* nw1T = (__half*)alloc(sz_nw1);
    __half* nw2T = (__half*)alloc(sz_nw2);

    {
        int tot;
        tot = NLAYER * THREE_H * TWO_H;
        transpose_cvt_kernel<<<(tot + 255) / 256, 256, 0, stream>>>(e_w1, ew1T, THREE_H, TWO_H, tot);
        tot = NLAYER * TWO_H * H;
        transpose_cvt_kernel<<<(tot + 255) / 256, 256, 0, stream>>>(e_w2, ew2T, TWO_H, H, tot);
        tot = NLAYER * TWO_H * TWO_H;
        transpose_cvt_kernel<<<(tot + 255) / 256, 256, 0, stream>>>(n_w1, nw1T, TWO_H, TWO_H, tot);
        tot = NLAYER * TWO_H * H;
        transpose_cvt_kernel<<<(tot + 255) / 256, 256, 0, stream>>>(n_w2, nw2T, TWO_H, H, tot);
    }

    encoder_kernel<<<NN, 128, 0, stream>>>(x, enc_w, enc_b, enc_g, enc_bb, hh);
    eenc_kernel<<<NE, 128, 0, stream>>>(eattr, eenc_w, eenc_b, ea);
    hipMemsetAsync(cnt, 0, (size_t)NN * 4, stream);
    count_kernel<<<(NE + 255) / 256, 256, 0, stream>>>(eidx + NE, cnt);
    scan_kernel<<<1, 1024, 0, stream>>>(cnt, rstart, cntf);
    init_fill_kernel<<<(NN + 255) / 256, 256, 0, stream>>>(rstart, fptr);
    fill_kernel<<<(NE + 255) / 256, 256, 0, stream>>>(eidx + NE, fptr, elist);

    for (int l = 0; l < NLAYER; l++) {
        mlp_mfma<true><<<NE / 64, 512, 0, stream>>>(
            hh, ea, nullptr, eidx,
            ew1T + (size_t)l * TWO_H * THREE_H, e_b1 + (size_t)l * TWO_H,
            e_g1 + (size_t)l * TWO_H, e_bb1 + (size_t)l * TWO_H,
            ew2T + (size_t)l * H * TWO_H, e_b2 + (size_t)l * H,
            e_g2 + (size_t)l * H, e_bb2 + (size_t)l * H,
            NE);
        aggregate_kernel<<<NN, 128, 0, stream>>>(ea, elist, rstart, cntf, agg);
        mlp_mfma<false><<<(NN + 63) / 64, 512, 0, stream>>>(
            hh, nullptr, agg, nullptr,
            nw1T + (size_t)l * TWO_H * TWO_H, n_b1 + (size_t)l * TWO_H,
            n_g1 + (size_t)l * TWO_H, n_bb1 + (size_t)l * TWO_H,
            nw2T + (size_t)l * H * TWO_H, n_b2 + (size_t)l * H,
            n_g2 + (size_t)l * H, n_bb2 + (size_t)l * H,
            NN);
    }
    decoder_kernel<<<NN, 128, 0, stream>>>(hh, dec_w1, dec_b1, dec_w2, dec_b2, out);
}

// Round 11
// 7631.452 us; speedup vs baseline: 1.0515x; 1.0515x over previous
//
#include <hip/hip_runtime.h>
#include <hip/hip_fp16.h>
#include <math.h>

#define NN 50000
#define NE 600000
#define H 128
#define TWO_H 256
#define THREE_H 384
#define NLAYER 10

typedef __attribute__((ext_vector_type(4))) float f32x4;
typedef __attribute__((ext_vector_type(8))) short s16x8;
typedef _Float16 f16x8 __attribute__((ext_vector_type(8)));

__device__ __forceinline__ float gelu_f(float x) {
    return 0.5f * x * (1.0f + erff(x * 0.70710678118654752f));
}

// tanh-form GELU: max |err vs exact| ~3e-4, ~9 VALU ops (HW v_exp/v_rcp)
__device__ __forceinline__ float gelu_fast(float x) {
    float u = x * fmaf(0.044715f, x * x, 1.0f);
    float e = __expf(1.5957691216057308f * u);
    return x * (1.0f - __builtin_amdgcn_rcpf(e + 1.0f));
}

__device__ __forceinline__ float wave_reduce_add64(float v) {
#pragma unroll
    for (int m = 32; m >= 1; m >>= 1) v += __shfl_xor(v, m);
    return v;
}

__global__ void signal_kernel(float* __restrict__ out, int n, float val) {
    int i = blockIdx.x * blockDim.x + threadIdx.x;
    if (i < n) out[i] = val;
}

// ---------------- weight prep: fp32 [L][K][N] -> fp16 [L][N][K] ----------------
__global__ void transpose_cvt_kernel(const float* __restrict__ src,
                                     __half* __restrict__ dst,
                                     int K, int N, int total) {
    int i = blockIdx.x * 256 + threadIdx.x;
    if (i >= total) return;
    int n = i % N;
    int lk = i / N;
    int k = lk % K;
    int l = lk / K;
    dst[((size_t)l * N + n) * K + k] = __float2half_rn(src[i]);
}

// ---------------- encoder: h = GELU(LN(x @ enc_w + enc_b)) -> fp16 ----------------
__global__ __launch_bounds__(128) void encoder_kernel(
    const float* __restrict__ x, const float* __restrict__ w,
    const float* __restrict__ b, const float* __restrict__ g,
    const float* __restrict__ bb, __half* __restrict__ hh) {
    int n = blockIdx.x;
    int j = threadIdx.x;
    __shared__ float xs[3];
    __shared__ float2 red[2];
    if (j < 3) xs[j] = x[n * 3 + j];
    __syncthreads();
    float v = b[j] + xs[0] * w[j] + xs[1] * w[H + j] + xs[2] * w[2 * H + j];
    float s = v, sq = v * v;
    s = wave_reduce_add64(s);
    sq = wave_reduce_add64(sq);
    if ((j & 63) == 0) red[j >> 6] = make_float2(s, sq);
    __syncthreads();
    float ts = red[0].x + red[1].x;
    float tq = red[0].y + red[1].y;
    float m = ts * (1.0f / 128.0f);
    float var = tq * (1.0f / 128.0f) - m * m;
    float rs = rsqrtf(var + 1e-5f);
    hh[(size_t)n * H + j] = __float2half_rn(gelu_f((v - m) * rs * g[j] + bb[j]));
}

// ---------------- edge encoder ----------------
__global__ __launch_bounds__(128) void eenc_kernel(
    const float* __restrict__ attr, const float* __restrict__ w,
    const float* __restrict__ b, __half* __restrict__ ea) {
    int e = blockIdx.x;
    int j = threadIdx.x;
    __shared__ float as_[8];
    if (j < 8) as_[j] = attr[(size_t)e * 8 + j];
    __syncthreads();
    float v = b[j];
#pragma unroll
    for (int k = 0; k < 8; k++) v += as_[k] * w[k * H + j];
    ea[(size_t)e * H + j] = __float2half_rn(v);
}

__global__ void count_kernel(const int* __restrict__ col, int* __restrict__ cnt) {
    int i = blockIdx.x * blockDim.x + threadIdx.x;
    if (i < NE) atomicAdd(&cnt[col[i]], 1);
}

__global__ __launch_bounds__(1024) void scan_kernel(
    const int* __restrict__ cnt, int* __restrict__ rstart, float* __restrict__ cntf) {
    __shared__ int buf[1024];
    __shared__ int s_carry;
    int tid = threadIdx.x;
    if (tid == 0) s_carry = 0;
    __syncthreads();
    for (int base = 0; base < NN; base += 1024) {
        int i = base + tid;
        int v = (i < NN) ? cnt[i] : 0;
        buf[tid] = v;
        __syncthreads();
        for (int off = 1; off < 1024; off <<= 1) {
            int add = (tid >= off) ? buf[tid - off] : 0;
            __syncthreads();
            buf[tid] += add;
            __syncthreads();
        }
        int incl = buf[tid];
        int cv = s_carry;
        if (i < NN) {
            rstart[i] = cv + incl - v;
            cntf[i] = (float)(v > 1 ? v : 1);
        }
        __syncthreads();
        if (tid == 0) s_carry = cv + buf[1023];
        __syncthreads();
    }
    if (threadIdx.x == 0) rstart[NN] = s_carry;
}

__global__ void init_fill_kernel(const int* __restrict__ rstart, int* __restrict__ fptr) {
    int i = blockIdx.x * blockDim.x + threadIdx.x;
    if (i < NN) fptr[i] = rstart[i];
}

__global__ void fill_kernel(const int* __restrict__ col, int* __restrict__ fptr,
                            int* __restrict__ elist) {
    int i = blockIdx.x * blockDim.x + threadIdx.x;
    if (i < NE) {
        int c = col[i];
        int p = atomicAdd(&fptr[c], 1);
        elist[p] = i;
    }
}

// ---------------- CSR mean aggregation ----------------
__global__ __launch_bounds__(128) void aggregate_kernel(
    const __half* __restrict__ ea, const int* __restrict__ elist,
    const int* __restrict__ rstart, const float* __restrict__ cntf,
    __half* __restrict__ agg) {
    int n = blockIdx.x;
    int t = threadIdx.x;
    int s = rstart[n], e_end = rstart[n + 1];
    float sum = 0.0f;
    for (int p = s; p < e_end; ++p) {
        int e = elist[p];
        sum += __half2float(ea[(size_t)e * H + t]);
    }
    agg[(size_t)n * H + t] = __float2half_rn(sum / cntf[n]);
}

// ---------------- fused f16-MFMA MLP, 512 threads / 8 waves ----------------
// 64 rows/block. Wave w: GEMM1 cols [w*32,+32) (2 ct), GEMM2 cols [w*16,+16) (1 ct).
// NOTE: __launch_bounds__ 2nd arg is CUDA-style MIN BLOCKS PER CU on this toolchain
// (round-10 evidence: (512,6) -> 48 waves/CU -> VGPR capped to 40 -> massive spill,
// WRITE_SIZE 150->450MB). (512,3) -> 24 waves/CU -> VGPR cap 84, no spill expected.
// 3 blocks x 54.2KB LDS = 162.8KB <= 160KiB? 162816 <= 163840 ✓.
template <bool EDGE>
__global__ __launch_bounds__(512, 3) void mlp_mfma(
    __half* hh, __half* ea, const __half* __restrict__ agg,
    const int* __restrict__ eidx,
    const __half* __restrict__ w1T, const float* __restrict__ b1,
    const float* __restrict__ g1, const float* __restrict__ bb1,
    const __half* __restrict__ w2T, const float* __restrict__ b2,
    const float* __restrict__ g2, const float* __restrict__ bb2,
    int nrows) {
    constexpr int KIN = EDGE ? THREE_H : TWO_H;
    constexpr int ALD = KIN + 8;   // halves; odd word-stride rows
    constexpr int ZLD = TWO_H + 8; // 264

    __shared__ __align__(16) short A_s[64 * ALD];
    __shared__ float2 red[64][8];
    short* z_s = A_s;  // z tile [64][264] aliases A_s

    const int t = threadIdx.x;
    const int wave = t >> 6;      // 0..7
    const int lane = t & 63;
    const int lanelo = lane & 15;
    const int grp = lane >> 4;
    const size_t r0 = (size_t)blockIdx.x * 64;

    // ---- stage A: fp16 bit-copies, 8 threads per row ----
    {
        int r = t >> 3;      // 0..63
        int ph = t & 7;
        size_t row_g = r0 + r;
        const short* s0;
        const short* s1 = nullptr;
        const short* s2;
        if constexpr (EDGE) {
            int ri = eidx[row_g];
            int ci = eidx[NE + row_g];
            s0 = (const short*)hh + (size_t)ri * H;
            s1 = (const short*)hh + (size_t)ci * H;
            s2 = (const short*)ea + row_g * H;
        } else {
            size_t n = row_g < (size_t)nrows ? row_g : (size_t)(nrows - 1);
            s0 = (const short*)hh + n * H;
            s2 = (const short*)agg + n * H;
        }
        short* arow = A_s + r * ALD;
#pragma unroll
        for (int k = ph * 8; k < KIN; k += 64) {
            s16x8 sv;
            if constexpr (EDGE) {
                if (k < H) sv = *(const s16x8*)(s0 + k);
                else if (k < 2 * H) sv = *(const s16x8*)(s1 + (k - H));
                else sv = *(const s16x8*)(s2 + (k - 2 * H));
            } else {
                sv = (k < H) ? *(const s16x8*)(s0 + k) : *(const s16x8*)(s2 + (k - H));
            }
            *(s16x8*)(arow + k) = sv;
        }
    }
    __syncthreads();

    // ---- GEMM1: z[64][256] = A @ w1 (2 col-tiles per wave) ----
    f32x4 acc[4][2];
#pragma unroll
    for (int rt = 0; rt < 4; rt++)
#pragma unroll
        for (int ct = 0; ct < 2; ct++) acc[rt][ct] = (f32x4){0.f, 0.f, 0.f, 0.f};

    const int c1 = wave * 32 + lanelo;  // +ct*16
    for (int ks = 0; ks < KIN / 32; ++ks) {
        const int k0 = ks * 32 + grp * 8;
        f16x8 a[4], b[2];
#pragma unroll
        for (int rt = 0; rt < 4; rt++)
            a[rt] = *(const f16x8*)(const void*)(A_s + (rt * 16 + lanelo) * ALD + k0);
#pragma unroll
        for (int ct = 0; ct < 2; ct++)
            b[ct] = *(const f16x8*)(const void*)(w1T + (size_t)(c1 + ct * 16) * KIN + k0);
#pragma unroll
        for (int rt = 0; rt < 4; rt++)
#pragma unroll
            for (int ct = 0; ct < 2; ct++)
                acc[rt][ct] = __builtin_amdgcn_mfma_f32_16x16x32_f16(
                    a[rt], b[ct], acc[rt][ct], 0, 0, 0);
    }

    // ---- fold bias, LN1 partials ----
#pragma unroll
    for (int ct = 0; ct < 2; ct++) {
        float bc = b1[c1 + ct * 16];
#pragma unroll
        for (int rt = 0; rt < 4; rt++)
#pragma unroll
            for (int i = 0; i < 4; i++) acc[rt][ct][i] += bc;
    }
#pragma unroll
    for (int rt = 0; rt < 4; rt++)
#pragma unroll
        for (int i = 0; i < 4; i++) {
            float z0 = acc[rt][0][i], z1 = acc[rt][1][i];
            float s = z0 + z1;
            float q = z0 * z0 + z1 * z1;
            s += __shfl_xor(s, 1); s += __shfl_xor(s, 2);
            s += __shfl_xor(s, 4); s += __shfl_xor(s, 8);
            q += __shfl_xor(q, 1); q += __shfl_xor(q, 2);
            q += __shfl_xor(q, 4); q += __shfl_xor(q, 8);
            if (lanelo == 0) red[rt * 16 + grp * 4 + i][wave] = make_float2(s, q);
        }
    __syncthreads();  // fences A_s reads -> z_s writes safe

    // ---- LN1 apply + fast GELU + write z fp16 ----
    {
        float g1c[2], bb1c[2];
#pragma unroll
        for (int ct = 0; ct < 2; ct++) { g1c[ct] = g1[c1 + ct * 16]; bb1c[ct] = bb1[c1 + ct * 16]; }
#pragma unroll
        for (int rt = 0; rt < 4; rt++)
#pragma unroll
            for (int i = 0; i < 4; i++) {
                int r = rt * 16 + grp * 4 + i;
                float sum = 0.f, sq = 0.f;
#pragma unroll
                for (int w = 0; w < 8; w++) { float2 pw = red[r][w]; sum += pw.x; sq += pw.y; }
                float m = sum * (1.f / 256.f);
                float var = sq * (1.f / 256.f) - m * m;
                float rs = rsqrtf(var + 1e-5f);
#pragma unroll
                for (int ct = 0; ct < 2; ct++) {
                    float v = (acc[rt][ct][i] - m) * rs * g1c[ct] + bb1c[ct];
                    __half hv = __float2half_rn(gelu_fast(v));
                    z_s[r * ZLD + c1 + ct * 16] = __half_as_short(hv);
                }
            }
    }
    __syncthreads();

    // ---- GEMM2: d[64][128] = z @ w2 (1 col-tile per wave) ----
    f32x4 acc2[4];
#pragma unroll
    for (int rt = 0; rt < 4; rt++) acc2[rt] = (f32x4){0.f, 0.f, 0.f, 0.f};

    const int c2 = wave * 16 + lanelo;
    for (int ks = 0; ks < TWO_H / 32; ++ks) {
        const int k0 = ks * 32 + grp * 8;
        f16x8 a2[4], b2v;
#pragma unroll
        for (int rt = 0; rt < 4; rt++)
            a2[rt] = *(const f16x8*)(const void*)(z_s + (rt * 16 + lanelo) * ZLD + k0);
        b2v = *(const f16x8*)(const void*)(w2T + (size_t)c2 * TWO_H + k0);
#pragma unroll
        for (int rt = 0; rt < 4; rt++)
            acc2[rt] = __builtin_amdgcn_mfma_f32_16x16x32_f16(a2[rt], b2v, acc2[rt], 0, 0, 0);
    }

    // ---- fold bias, LN2 partials ----
    {
        float bc = b2[c2];
#pragma unroll
        for (int rt = 0; rt < 4; rt++)
#pragma unroll
            for (int i = 0; i < 4; i++) acc2[rt][i] += bc;
    }
#pragma unroll
    for (int rt = 0; rt < 4; rt++)
#pragma unroll
        for (int i = 0; i < 4; i++) {
            float z = acc2[rt][i];
            float s = z, q = z * z;
            s += __shfl_xor(s, 1); s += __shfl_xor(s, 2);
            s += __shfl_xor(s, 4); s += __shfl_xor(s, 8);
            q += __shfl_xor(q, 1); q += __shfl_xor(q, 2);
            q += __shfl_xor(q, 4); q += __shfl_xor(q, 8);
            if (lanelo == 0) red[rt * 16 + grp * 4 + i][wave] = make_float2(s, q);
        }
    __syncthreads();

    // ---- LN2 apply + residual RMW (fp16 state) ----
    {
        float g2c = g2[c2], bb2c = bb2[c2];
#pragma unroll
        for (int rt = 0; rt < 4; rt++)
#pragma unroll
            for (int i = 0; i < 4; i++) {
                int r = rt * 16 + grp * 4 + i;
                float sum = 0.f, sq = 0.f;
#pragma unroll
                for (int w = 0; w < 8; w++) { float2 pw = red[r][w]; sum += pw.x; sq += pw.y; }
                float m = sum * (1.f / 128.f);
                float var = sq * (1.f / 128.f) - m * m;
                float rs = rsqrtf(var + 1e-5f);
                size_t rowg = r0 + r;
                float d = (acc2[rt][i] - m) * rs * g2c + bb2c;
                size_t idx = rowg * H + c2;
                if constexpr (EDGE) {
                    ea[idx] = __float2half_rn(__half2float(ea[idx]) + d);
                } else {
                    if (rowg < (size_t)nrows)
                        hh[idx] = __float2half_rn(__half2float(hh[idx]) + d);
                }
            }
    }
}

// ---------------- decoder ----------------
__global__ __launch_bounds__(128) void decoder_kernel(
    const __half* __restrict__ hh, const float* __restrict__ w1,
    const float* __restrict__ b1, const float* __restrict__ w2,
    const float* __restrict__ b2, float* __restrict__ out) {
    int n = blockIdx.x;
    int j = threadIdx.x;
    __shared__ float hs[128];
    __shared__ float4 red[2];
    hs[j] = __half2float(hh[(size_t)n * H + j]);
    __syncthreads();
    float t1 = b1[j];
#pragma unroll 8
    for (int k = 0; k < 128; k++) t1 += hs[k] * w1[k * H + j];
    t1 = gelu_f(t1);
    float4 w = *(const float4*)(w2 + j * 4);
    float4 p = make_float4(t1 * w.x, t1 * w.y, t1 * w.z, t1 * w.w);
#pragma unroll
    for (int m = 32; m >= 1; m >>= 1) {
        p.x += __shfl_xor(p.x, m);
        p.y += __shfl_xor(p.y, m);
        p.z += __shfl_xor(p.z, m);
        p.w += __shfl_xor(p.w, m);
    }
    if ((j & 63) == 0) red[j >> 6] = p;
    __syncthreads();
    if (j == 0) {
        out[(size_t)n * 4 + 0] = red[0].x + red[1].x + b2[0];
        out[(size_t)n * 4 + 1] = red[0].y + red[1].y + b2[1];
        out[(size_t)n * 4 + 2] = red[0].z + red[1].z + b2[2];
        out[(size_t)n * 4 + 3] = red[0].w + red[1].w + b2[3];
    }
}

extern "C" void kernel_launch(void* const* d_in, const int* in_sizes, int n_in,
                              void* d_out, int out_size, void* d_ws, size_t ws_size,
                              hipStream_t stream) {
    const float* x = (const float*)d_in[0];
    const int* eidx = (const int*)d_in[1];
    const float* eattr = (const float*)d_in[2];
    const float* enc_w = (const float*)d_in[3];
    const float* enc_b = (const float*)d_in[4];
    const float* enc_g = (const float*)d_in[5];
    const float* enc_bb = (const float*)d_in[6];
    const float* eenc_w = (const float*)d_in[7];
    const float* eenc_b = (const float*)d_in[8];
    const float* e_w1 = (const float*)d_in[9];
    const float* e_b1 = (const float*)d_in[10];
    const float* e_g1 = (const float*)d_in[11];
    const float* e_bb1 = (const float*)d_in[12];
    const float* e_w2 = (const float*)d_in[13];
    const float* e_b2 = (const float*)d_in[14];
    const float* e_g2 = (const float*)d_in[15];
    const float* e_bb2 = (const float*)d_in[16];
    const float* n_w1 = (const float*)d_in[17];
    const float* n_b1 = (const float*)d_in[18];
    const float* n_g1 = (const float*)d_in[19];
    const float* n_bb1 = (const float*)d_in[20];
    const float* n_w2 = (const float*)d_in[21];
    const float* n_b2 = (const float*)d_in[22];
    const float* n_g2 = (const float*)d_in[23];
    const float* n_bb2 = (const float*)d_in[24];
    const float* dec_w1 = (const float*)d_in[25];
    const float* dec_b1 = (const float*)d_in[26];
    const float* dec_w2 = (const float*)d_in[27];
    const float* dec_b2 = (const float*)d_in[28];
    float* out = (float*)d_out;
    (void)in_sizes; (void)n_in;

    auto AL = [](size_t b) { return (b + 255) & ~(size_t)255; };
    const size_t sz_hh = AL((size_t)NN * H * 2);
    const size_t sz_ea = AL((size_t)NE * H * 2);
    const size_t sz_agg = AL((size_t)NN * H * 2);
    const size_t sz_cntf = AL((size_t)NN * 4);
    const size_t sz_cnt = AL((size_t)NN * 4);
    const size_t sz_rst = AL((size_t)(NN + 1) * 4);
    const size_t sz_fptr = AL((size_t)NN * 4);
    const size_t sz_elist = AL((size_t)NE * 4);
    const size_t sz_ew1 = AL((size_t)NLAYER * TWO_H * THREE_H * 2);
    const size_t sz_ew2 = AL((size_t)NLAYER * H * TWO_H * 2);
    const size_t sz_nw1 = AL((size_t)NLAYER * TWO_H * TWO_H * 2);
    const size_t sz_nw2 = AL((size_t)NLAYER * H * TWO_H * 2);
    const size_t need = sz_hh + sz_ea + sz_agg + sz_cntf + sz_cnt + sz_rst +
                        sz_fptr + sz_elist + sz_ew1 + sz_ew2 + sz_nw1 + sz_nw2;

    if (ws_size < need) {
        float sig = 1000.0f + (float)(ws_size >> 20);
        signal_kernel<<<(out_size + 255) / 256, 256, 0, stream>>>(out, out_size, sig);
        return;
    }

    char* p = (char*)d_ws;
    auto alloc = [&](size_t bytes) { void* r = (void*)p; p += bytes; return r; };
    __half* hh = (__half*)alloc(sz_hh);
    __half* ea = (__half*)alloc(sz_ea);
    __half* agg = (__half*)alloc(sz_agg);
    float* cntf = (float*)alloc(sz_cntf);
    int* cnt = (int*)alloc(sz_cnt);
    int* rstart = (int*)alloc(sz_rst);
    int* fptr = (int*)alloc(sz_fptr);
    int* elist = (int*)alloc(sz_elist);
    __half* ew1T = (__half*)alloc(sz_ew1);
    __half* ew2T = (__half*)alloc(sz_ew2);
    __half* nw1T = (__half*)alloc(sz_nw1);
    __half* nw2T = (__half*)alloc(sz_nw2);

    {
        int tot;
        tot = NLAYER * THREE_H * TWO_H;
        transpose_cvt_kernel<<<(tot + 255) / 256, 256, 0, stream>>>(e_w1, ew1T, THREE_H, TWO_H, tot);
        tot = NLAYER * TWO_H * H;
        transpose_cvt_kernel<<<(tot + 255) / 256, 256, 0, stream>>>(e_w2, ew2T, TWO_H, H, tot);
        tot = NLAYER * TWO_H * TWO_H;
        transpose_cvt_kernel<<<(tot + 255) / 256, 256, 0, stream>>>(n_w1, nw1T, TWO_H, TWO_H, tot);
        tot = NLAYER * TWO_H * H;
        transpose_cvt_kernel<<<(tot + 255) / 256, 256, 0, stream>>>(n_w2, nw2T, TWO_H, H, tot);
    }

    encoder_kernel<<<NN, 128, 0, stream>>>(x, enc_w, enc_b, enc_g, enc_bb, hh);
    eenc_kernel<<<NE, 128, 0, stream>>>(eattr, eenc_w, eenc_b, ea);
    hipMemsetAsync(cnt, 0, (size_t)NN * 4, stream);
    count_kernel<<<(NE + 255) / 256, 256, 0, stream>>>(eidx + NE, cnt);
    scan_kernel<<<1, 1024, 0, stream>>>(cnt, rstart, cntf);
    init_fill_kernel<<<(NN + 255) / 256, 256, 0, stream>>>(rstart, fptr);
    fill_kernel<<<(NE + 255) / 256, 256, 0, stream>>>(eidx + NE, fptr, elist);

    for (int l = 0; l < NLAYER; l++) {
        mlp_mfma<true><<<NE / 64, 512, 0, stream>>>(
            hh, ea, nullptr, eidx,
            ew1T + (size_t)l * TWO_H * THREE_H, e_b1 + (size_t)l * TWO_H,
            e_g1 + (size_t)l * TWO_H, e_bb1 + (size_t)l * TWO_H,
            ew2T + (size_t)l * H * TWO_H, e_b2 + (size_t)l * H,
            e_g2 + (size_t)l * H, e_bb2 + (size_t)l * H,
            NE);
        aggregate_kernel<<<NN, 128, 0, stream>>>(ea, elist, rstart, cntf, agg);
        mlp_mfma<false><<<(NN + 63) / 64, 512, 0, stream>>>(
            hh, nullptr, agg, nullptr,
            nw1T + (size_t)l * TWO_H * TWO_H, n_b1 + (size_t)l * TWO_H,
            n_g1 + (size_t)l * TWO_H, n_bb1 + (size_t)l * TWO_H,
            nw2T + (size_t)l * H * TWO_H, n_b2 + (size_t)l * H,
            n_g2 + (size_t)l * H, n_bb2 + (size_t)l * H,
            NN);
    }
    decoder_kernel<<<NN, 128, 0, stream>>>(hh, dec_w1, dec_b1, dec_w2, dec_b2, out);
}